// Round 9
// baseline (216.051 us; speedup 1.0000x reference)
//
#include <hip/hip_runtime.h>
#include <hip/hip_bf16.h>

#define BATCH 4
#define SEQ   2048
#define DIN   1024
#define DOUT  1024
#define MTOT  (BATCH*SEQ)

typedef __hip_bfloat16 bf16;
typedef __attribute__((ext_vector_type(8))) short bf16x8;
typedef __attribute__((ext_vector_type(4))) float f32x4;

#define MFMA(a,b,c) __builtin_amdgcn_mfma_f32_16x16x32_bf16(a,b,c,0,0,0)

union pack4 { bf16 h[4]; uint2 u2; };
union pack8 { bf16 h[8]; bf16x8 v; };

// async 16B global->LDS (DMA, no VGPR round-trip)
__device__ __forceinline__ void gl16(const bf16* g, bf16* l)
{
    __builtin_amdgcn_global_load_lds(
        (const __attribute__((address_space(1))) void*)g,
        (__attribute__((address_space(3))) void*)l, 16, 0, 0);
}

// ---------------- prep: M = Wq.Wk^T tiles, x cast, Wv transpose, RS zero ----
// scores = Q K^T = x (Wq Wk^T) x^T, so K is NEVER computed: qkv later does
// Q' = xb @ Mt (B-operand Mt[b][a] = sum_n Wk[b][n] Wq[a][n]) and V only.
// M-blocks (bid 0..255) read fp32 W directly (reg-staged cast, 64x64 tiles,
// ~4 K-step-equiv/CU) and hide under the 8192-block x-cast stream.

__global__ __launch_bounds__(256)
void k_prep(const float* __restrict__ x, const float* __restrict__ Wq,
            const float* __restrict__ Wk, const float* __restrict__ Wv,
            bf16* __restrict__ xb, bf16* __restrict__ Wtv,
            bf16* __restrict__ Mt, float* __restrict__ RS)
{
    __shared__ __align__(16) bf16 smem[8192];      // 16 KB (M: As|Bs; WvT: t)
    const int bid = blockIdx.x;
    const int tid = threadIdx.x;

    if (bid < 256) {                               // ---- M tile 64x64
        bf16* As = smem;                           // [64][64] swizzled
        bf16* Bs = smem + 4096;
        const int m0 = (bid >> 4) * 64;            // Wk row (b, d_in)
        const int n0 = (bid & 15) * 64;            // Wq row (a, d_in)
        const int lane = tid & 63, wave = tid >> 6;
        const int wm = (wave >> 1) * 32, wn = (wave & 1) * 32;
        const int r = lane & 15, qd = lane >> 4;
        f32x4 acc[2][2] = {};
        for (int kk = 0; kk < 16; ++kk) {
#pragma unroll
            for (int j = 0; j < 2; ++j) {
                int ch = tid * 2 + j;              // 0..511
                int row = ch >> 3, cc = ch & 7;
                int dst = row * 64 + ((cc ^ (row & 7)) * 8);
                const float* pa = Wk + (long)(m0 + row) * 1024 + kk * 64 + cc * 8;
                float4 a0 = *(const float4*)pa, a1 = *(const float4*)(pa + 4);
                pack8 o;
                o.h[0] = __float2bfloat16(a0.x); o.h[1] = __float2bfloat16(a0.y);
                o.h[2] = __float2bfloat16(a0.z); o.h[3] = __float2bfloat16(a0.w);
                o.h[4] = __float2bfloat16(a1.x); o.h[5] = __float2bfloat16(a1.y);
                o.h[6] = __float2bfloat16(a1.z); o.h[7] = __float2bfloat16(a1.w);
                *(bf16x8*)&As[dst] = o.v;
                const float* pb = Wq + (long)(n0 + row) * 1024 + kk * 64 + cc * 8;
                float4 b0 = *(const float4*)pb, b1 = *(const float4*)(pb + 4);
                o.h[0] = __float2bfloat16(b0.x); o.h[1] = __float2bfloat16(b0.y);
                o.h[2] = __float2bfloat16(b0.z); o.h[3] = __float2bfloat16(b0.w);
                o.h[4] = __float2bfloat16(b1.x); o.h[5] = __float2bfloat16(b1.y);
                o.h[6] = __float2bfloat16(b1.z); o.h[7] = __float2bfloat16(b1.w);
                *(bf16x8*)&Bs[dst] = o.v;
            }
            __syncthreads();
#pragma unroll
            for (int ks = 0; ks < 2; ++ks) {
                const int slot = ((ks * 4 + qd) ^ (r & 7)) * 8;
                bf16x8 af[2], bv[2];
#pragma unroll
                for (int mi = 0; mi < 2; ++mi)
                    af[mi] = *(const bf16x8*)&As[(wm + mi * 16 + r) * 64 + slot];
#pragma unroll
                for (int ni = 0; ni < 2; ++ni)
                    bv[ni] = *(const bf16x8*)&Bs[(wn + ni * 16 + r) * 64 + slot];
#pragma unroll
                for (int mi = 0; mi < 2; ++mi)
#pragma unroll
                    for (int ni = 0; ni < 2; ++ni)
                        acc[mi][ni] = MFMA(af[mi], bv[ni], acc[mi][ni]);
            }
            __syncthreads();
        }
#pragma unroll
        for (int mi = 0; mi < 2; ++mi)
#pragma unroll
            for (int ni = 0; ni < 2; ++ni)
#pragma unroll
                for (int j = 0; j < 4; ++j) {
                    int row = m0 + wm + mi * 16 + qd * 4 + j;   // b
                    int col = n0 + wn + ni * 16 + r;            // a
                    Mt[(long)row * 1024 + col] = __float2bfloat16(acc[mi][ni][j]);
                }
        return;
    }
    if (bid < 8448) {                              // ---- x cast (8192 blocks)
        long i = ((long)(bid - 256) * 256 + tid) * 4;
        float4 v = *(const float4*)(x + i);
        pack4 o;
        o.h[0] = __float2bfloat16(v.x);
        o.h[1] = __float2bfloat16(v.y);
        o.h[2] = __float2bfloat16(v.z);
        o.h[3] = __float2bfloat16(v.w);
        *(uint2*)(xb + i) = o.u2;
        return;
    }
    if (bid >= 8704) {                             // ---- RS zero (8 blocks)
        int i = (bid - 8704) * 1024 + tid * 4;
        *(float4*)(RS + i) = make_float4(0.f, 0.f, 0.f, 0.f);
        return;
    }
    // ---- Wv transpose (256 blocks)
    const int idx = bid - 8448;                    // 0..255
    const int k0 = (idx >> 4) * 64, n0 = (idx & 15) * 64;
    bf16* t = smem;                                // [64][68]
#pragma unroll
    for (int p = 0; p < 4; ++p) {
        int kr = p * 16 + (tid >> 4);
        int c4 = (tid & 15) * 4;
        float4 v = *(const float4*)&Wv[(long)(k0 + kr) * DOUT + n0 + c4];
        t[(c4 + 0) * 68 + kr] = __float2bfloat16(v.x);
        t[(c4 + 1) * 68 + kr] = __float2bfloat16(v.y);
        t[(c4 + 2) * 68 + kr] = __float2bfloat16(v.z);
        t[(c4 + 3) * 68 + kr] = __float2bfloat16(v.w);
    }
    __syncthreads();
#pragma unroll
    for (int i = 0; i < 2; ++i) {
        int l = tid + i * 256;
        int n = l >> 3, c8 = (l & 7) * 8;
        pack8 o;
#pragma unroll
        for (int j = 0; j < 8; ++j) o.h[j] = t[n * 68 + c8 + j];
        *(bf16x8*)&Wtv[(long)(n0 + n) * DIN + k0 + c8] = o.v;
    }
}

// ---------------- shared GEMM core, BK=64 (round-0 verified) ----------------
// DIAG=1: skip fully-masked subtiles on scores diagonal tiles (bit-identical
// output; masked outputs are forced to 0 in the epilogue).

template<int DIAG>
__device__ __forceinline__ void gemm_core(
    const bf16* __restrict__ Ab, long lda,
    const bf16* __restrict__ Bb, long ldb,
    int nk, bf16* __restrict__ As, bf16* __restrict__ Bs,
    f32x4 acc[4][4])
{
    const int tid  = threadIdx.x;
    const int lane = tid & 63;
    const int wave = tid >> 6;
    const int wm = (wave >> 1) * 64;
    const int wn = (wave & 1) * 64;
    const int r  = lane & 15;
    const int qd = lane >> 4;

    const bool skipWave = DIAG && (wn > wm);
    const bool sameOff  = DIAG && (wn == wm);

    const int row0 = tid >> 3;                    // 0..31
    const int c    = (tid & 7) ^ (row0 & 7);      // swizzled source chunk
    const long aoff = (long)row0 * lda + c * 8;
    const long boff = (long)row0 * ldb + c * 8;
    const long astep = 32 * lda, bstep = 32 * ldb;
    bf16* dA = &As[tid * 8];
    bf16* dB = &Bs[tid * 8];

    for (int kk = 0; kk < nk; ++kk) {
        const bf16* A = Ab + kk * 64 + aoff;
        const bf16* B = Bb + kk * 64 + boff;
#pragma unroll
        for (int i = 0; i < 4; ++i) {
            gl16(A + i * astep, dA + i * 2048);
            gl16(B + i * bstep, dB + i * 2048);
        }
        __syncthreads();                           // drains vmcnt
        if (!skipWave) {
#pragma unroll
            for (int ks = 0; ks < 2; ++ks) {
                const int slot = ((ks * 4 + qd) ^ (r & 7)) * 8;
                bf16x8 af[4], bv[4];
#pragma unroll
                for (int mi = 0; mi < 4; ++mi)
                    af[mi] = *(const bf16x8*)&As[(wm + mi * 16 + r) * 64 + slot];
#pragma unroll
                for (int ni = 0; ni < 4; ++ni)
                    bv[ni] = *(const bf16x8*)&Bs[(wn + ni * 16 + r) * 64 + slot];
#pragma unroll
                for (int mi = 0; mi < 4; ++mi)
#pragma unroll
                    for (int ni = 0; ni < 4; ++ni) {
                        if (sameOff && ni > mi) continue;   // fully masked
                        acc[mi][ni] = MFMA(af[mi], bv[ni], acc[mi][ni]);
                    }
            }
        }
        __syncthreads();
    }
}

// ---------------- Q'|V projection (16 n-tiles; K eliminated) ----------------
// bx 0..7:  Q' = xb @ Mt  -> Qp[row][1024]
// bx 8..15: V  = xb @ Wtv -> Vt[b][d][s] (transpose via LDS, as verified)

__global__ __launch_bounds__(256)
void k_gemm_qkv(const bf16* __restrict__ xb, const bf16* __restrict__ Mt,
                const bf16* __restrict__ Wtv, bf16* __restrict__ Qp,
                bf16* __restrict__ Vt)
{
    __shared__ __align__(16) bf16 smem[17408];    // As|Bs then T
    bf16* As = smem;
    bf16* Bs = smem + 8192;
    const int m0 = blockIdx.y * 128;
    const int bx = blockIdx.x;
    const int n0 = bx * 128;
    const bf16* Bpan = (bx < 8) ? (Mt + (long)n0 * DIN)
                                : (Wtv + (long)(n0 - 1024) * DIN);
    f32x4 acc[4][4] = {};
    gemm_core<0>(xb + (long)m0 * DIN, DIN, Bpan, DIN, DIN / 64, As, Bs, acc);

    const int tid = threadIdx.x;
    const int lane = tid & 63, wave = tid >> 6;
    const int wm = (wave >> 1) * 64, wn = (wave & 1) * 64;
    const int r = lane & 15, qd = lane >> 4;

    if (bx < 8) {                                  // Q': direct store
#pragma unroll
        for (int mi = 0; mi < 4; ++mi)
#pragma unroll
            for (int ni = 0; ni < 4; ++ni)
#pragma unroll
                for (int j = 0; j < 4; ++j) {
                    int row = m0 + wm + mi * 16 + qd * 4 + j;
                    int col = n0 + wn + ni * 16 + r;
                    Qp[(long)row * 1024 + col] = __float2bfloat16(acc[mi][ni][j]);
                }
    } else {                                       // V: transpose via LDS
        const int ld = 136;
        bf16* T = smem;                            // reuse (post-barrier)
#pragma unroll
        for (int mi = 0; mi < 4; ++mi)
#pragma unroll
            for (int ni = 0; ni < 4; ++ni) {
                pack4 p;
#pragma unroll
                for (int j = 0; j < 4; ++j) p.h[j] = __float2bfloat16(acc[mi][ni][j]);
                int d_l = wn + ni * 16 + r;
                int s_l = wm + mi * 16 + qd * 4;
                *(uint2*)&T[d_l * ld + s_l] = p.u2;
            }
        __syncthreads();
        const int n0v = n0 - 1024;
        const int bb = m0 >> 11;                   // batch index
        const int s0 = m0 & 2047;                  // seq offset within batch
        bf16* Ob = Vt + (long)bb * DOUT * SEQ + s0;
#pragma unroll
        for (int p = 0; p < 8; ++p) {
            int l = tid + p * 256;                 // 0..2047
            int d = l >> 4, s8 = (l & 15) * 8;
            bf16x8 vv = *(const bf16x8*)&T[d * ld + s8];
            *(bf16x8*)&Ob[(long)(n0v + d) * SEQ + s8] = vv;
        }
    }
}

// ---------------- scores: (Q' @ xb^T), exp, row-sum ----------------
// B-panel is xb itself (K eliminated). 544 blocks; diag tiles (DIAG-skip,
// ~0.61 cost) at bids 256..287 and 512..543 so the 32 straggler CUs
// (round-robin c, c+256, c+512) get TWO cheap tiles: critical path
// 16+9.75+9.75 = 35.5 K-steps vs round-8's 41.75.

__global__ __launch_bounds__(256, 3)
void k_gemm_scores(const bf16* __restrict__ Qp, const bf16* __restrict__ xb,
                   bf16* __restrict__ P, float* __restrict__ rowSum)
{
    const int bid = blockIdx.x;
    int b, qt, kt, u = -1, d = -1;
    if      (bid < 256) u = bid;
    else if (bid < 288) d = bid - 256;
    else if (bid < 512) u = bid - 32;
    else                d = bid - 480;
    if (u >= 0) {
        b = u & 3;
        int v = u >> 2;                            // 0..119, heavy qt first
        qt = 15;
        while (v >= qt) { v -= qt; --qt; }
        kt = v;                                    // kt < qt
    } else { b = d & 3; qt = kt = d >> 2; }

    __shared__ __align__(16) bf16 smem[17408];     // As|Bs then bounce tile
    bf16* As = smem;
    bf16* Bs = smem + 8192;
    const bf16* A  = Qp + (long)(b * SEQ + qt * 128) * 1024;
    const bf16* Bt = xb + (long)(b * SEQ + kt * 128) * 1024;
    f32x4 acc[4][4] = {};
    if (u >= 0) gemm_core<0>(A, 1024, Bt, 1024, DIN / 64, As, Bs, acc);
    else        gemm_core<1>(A, 1024, Bt, 1024, DIN / 64, As, Bs, acc);

    bf16* Pb = P + (long)b * SEQ * SEQ;
    float* RS = rowSum + b * SEQ;
    const int tid = threadIdx.x;
    const int lane = tid & 63, wave = tid >> 6;
    const int wm = (wave >> 1) * 64, wn = (wave & 1) * 64;
    const int r = lane & 15, qd = lane >> 4;

    const int ld = 136;                            // bounce-tile stride
    bf16* T = smem;                                // reuse (post-barrier)

    float rp[4][4];
#pragma unroll
    for (int mi = 0; mi < 4; ++mi)
#pragma unroll
        for (int j = 0; j < 4; ++j) rp[mi][j] = 0.f;

#pragma unroll
    for (int mi = 0; mi < 4; ++mi)
#pragma unroll
        for (int ni = 0; ni < 4; ++ni)
#pragma unroll
            for (int j = 0; j < 4; ++j) {
                int row_l = wm + mi * 16 + qd * 4 + j;
                int col_l = wn + ni * 16 + r;
                int row = qt * 128 + row_l;
                int col = kt * 128 + col_l;
                float e = (col > row) ? 0.f : __expf(acc[mi][ni][j] * 0.03125f);
                rp[mi][j] += e;
                T[row_l * ld + col_l] = __float2bfloat16(e);
            }
#pragma unroll
    for (int dd = 1; dd < 16; dd <<= 1)
#pragma unroll
        for (int mi = 0; mi < 4; ++mi)
#pragma unroll
            for (int j = 0; j < 4; ++j)
                rp[mi][j] += __shfl_xor(rp[mi][j], dd, 64);
    if (r == 0) {
#pragma unroll
        for (int mi = 0; mi < 4; ++mi)
#pragma unroll
            for (int j = 0; j < 4; ++j) {
                int row = qt * 128 + wm + mi * 16 + qd * 4 + j;
                atomicAdd(&RS[row], rp[mi][j]);
            }
    }
    __syncthreads();
    // bulk coalesced P store: 128x128 tile, b128 per thread x8
#pragma unroll
    for (int p = 0; p < 8; ++p) {
        int l = tid + p * 256;                     // 0..2047
        int row_l = l >> 4, c8 = (l & 15) * 8;
        bf16x8 vv = *(const bf16x8*)&T[row_l * ld + c8];
        *(bf16x8*)&Pb[(long)(qt * 128 + row_l) * SEQ + kt * 128 + c8] = vv;
    }
}

// ---------------- PV: O = (P @ V) / rowSum (round-6 verified) ----------------

__global__ __launch_bounds__(256, 3)
void k_gemm_pv(const bf16* __restrict__ P, const bf16* __restrict__ Vt,
               const float* __restrict__ rowSum, float* __restrict__ O)
{
    const int bid = blockIdx.x;                    // 0..511
    const int h   = bid & 255;
    const int qt  = (bid < 256) ? (15 - (h >> 5)) : (h >> 5);
    const int b   = (h >> 3) & 3;
    const int nt  = h & 7;
    __shared__ __align__(16) bf16 As[128 * 64];
    __shared__ __align__(16) bf16 Bs[128 * 64];
    const bf16* A  = P + (long)b * SEQ * SEQ + (long)qt * 128 * SEQ;
    const bf16* Bt = Vt + (long)b * DOUT * SEQ;
    const int nk = (qt + 1) * 2;                   // K up to (qt+1)*128, BK=64
    f32x4 acc[4][4] = {};
    gemm_core<0>(A, SEQ, Bt + (long)nt * 128 * SEQ, SEQ, nk, As, Bs, acc);

    float* Ob = O + (long)b * SEQ * DOUT;
    const float* RS = rowSum + b * SEQ;
    const int lane = threadIdx.x & 63, wave = threadIdx.x >> 6;
    const int wm = (wave >> 1) * 64, wn = (wave & 1) * 64;
    const int r = lane & 15, qd = lane >> 4;
#pragma unroll
    for (int mi = 0; mi < 4; ++mi)
#pragma unroll
        for (int j = 0; j < 4; ++j) {
            int row = qt * 128 + wm + mi * 16 + qd * 4 + j;
            float inv = 1.0f / RS[row];
#pragma unroll
            for (int ni = 0; ni < 4; ++ni) {
                int col = nt * 128 + wn + ni * 16 + r;
                Ob[(long)row * DOUT + col] = acc[mi][ni][j] * inv;
            }
        }
}

// ---------------- launch ----------------

extern "C" void kernel_launch(void* const* d_in, const int* in_sizes, int n_in,
                              void* d_out, int out_size, void* d_ws, size_t ws_size,
                              hipStream_t stream)
{
    const float* x  = (const float*)d_in[0];
    const float* Wq = (const float*)d_in[1];
    const float* Wk = (const float*)d_in[2];
    const float* Wv = (const float*)d_in[3];
    float* out = (float*)d_out;

    char* ws = (char*)d_ws;
    bf16*  xb  = (bf16*)(ws);                       // 16 MiB
    bf16*  Wtv = (bf16*)(ws + 16777216);            //  2 MiB
    bf16*  Mt  = (bf16*)(ws + 18874368);            //  2 MiB
    bf16*  Qp  = (bf16*)(ws + 20971520);            // 16 MiB
    bf16*  Vt  = (bf16*)(ws + 37748736);            // 16 MiB
    bf16*  P   = (bf16*)(ws + 54525952);            // 32 MiB
    float* RS  = (float*)(ws + 88080384);           // 32 KiB (total ~84 MiB)

    k_prep<<<dim3(256 + 8192 + 256 + 8), 256, 0, stream>>>(
        x, Wq, Wk, Wv, xb, Wtv, Mt, RS);
    k_gemm_qkv<<<dim3(16, MTOT / 128), 256, 0, stream>>>(xb, Mt, Wtv, Qp, Vt);
    k_gemm_scores<<<dim3(544), 256, 0, stream>>>(Qp, xb, P, RS);
    k_gemm_pv<<<dim3(512), 256, 0, stream>>>(P, Vt, RS, out);
}

// Round 10
// 215.248 us; speedup vs baseline: 1.0037x; 1.0037x over previous
//
#include <hip/hip_runtime.h>
#include <hip/hip_bf16.h>

#define BATCH 4
#define SEQ   2048
#define DIN   1024
#define DOUT  1024
#define MTOT  (BATCH*SEQ)

typedef __hip_bfloat16 bf16;
typedef __attribute__((ext_vector_type(8))) short bf16x8;
typedef __attribute__((ext_vector_type(4))) float f32x4;

#define MFMA(a,b,c) __builtin_amdgcn_mfma_f32_16x16x32_bf16(a,b,c,0,0,0)

union pack4 { bf16 h[4]; uint2 u2; };
union pack8 { bf16 h[8]; bf16x8 v; };

// async 16B global->LDS (DMA, no VGPR round-trip)
__device__ __forceinline__ void gl16(const bf16* g, bf16* l)
{
    __builtin_amdgcn_global_load_lds(
        (const __attribute__((address_space(1))) void*)g,
        (__attribute__((address_space(3))) void*)l, 16, 0, 0);
}

// ---------------- prep: split-K M partials, x cast, Wv transpose, RS ----
// M = Wq.Wk^T (K never computed downstream). Split-K: 4 blocks per 64x64
// M-tile, each covers K-quarter (4 serial K-iters, ~2-3 us latency -> hides
// under the 8192-block x-cast stream; round-9's 16-serial-iter version
// extended prep by ~10-15 us). Partials in fp32 Mp[4]; k_mcast sums+casts.

__global__ __launch_bounds__(256)
void k_prep(const float* __restrict__ x, const float* __restrict__ Wq,
            const float* __restrict__ Wk, const float* __restrict__ Wv,
            bf16* __restrict__ xb, bf16* __restrict__ Wtv,
            float* __restrict__ Mp, float* __restrict__ RS)
{
    __shared__ __align__(16) bf16 smem[8192];      // 16 KB
    const int bid = blockIdx.x;
    const int tid = threadIdx.x;

    if (bid < 1024) {                              // ---- M partial (split-K)
        bf16* As = smem;                           // [64][64] swizzled
        bf16* Bs = smem + 4096;
        const int tile = bid >> 2, kc = bid & 3;
        const int m0 = (tile >> 4) * 64;           // Wk row (b)
        const int n0 = (tile & 15) * 64;           // Wq row (a)
        const int lane = tid & 63, wave = tid >> 6;
        const int wm = (wave >> 1) * 32, wn = (wave & 1) * 32;
        const int r = lane & 15, qd = lane >> 4;
        f32x4 acc[2][2] = {};
        for (int kk = kc * 4; kk < kc * 4 + 4; ++kk) {
#pragma unroll
            for (int j = 0; j < 2; ++j) {
                int ch = tid * 2 + j;              // 0..511
                int row = ch >> 3, cc = ch & 7;
                int dst = row * 64 + ((cc ^ (row & 7)) * 8);
                const float* pa = Wk + (long)(m0 + row) * 1024 + kk * 64 + cc * 8;
                float4 a0 = *(const float4*)pa, a1 = *(const float4*)(pa + 4);
                pack8 o;
                o.h[0] = __float2bfloat16(a0.x); o.h[1] = __float2bfloat16(a0.y);
                o.h[2] = __float2bfloat16(a0.z); o.h[3] = __float2bfloat16(a0.w);
                o.h[4] = __float2bfloat16(a1.x); o.h[5] = __float2bfloat16(a1.y);
                o.h[6] = __float2bfloat16(a1.z); o.h[7] = __float2bfloat16(a1.w);
                *(bf16x8*)&As[dst] = o.v;
                const float* pb = Wq + (long)(n0 + row) * 1024 + kk * 64 + cc * 8;
                float4 b0 = *(const float4*)pb, b1 = *(const float4*)(pb + 4);
                o.h[0] = __float2bfloat16(b0.x); o.h[1] = __float2bfloat16(b0.y);
                o.h[2] = __float2bfloat16(b0.z); o.h[3] = __float2bfloat16(b0.w);
                o.h[4] = __float2bfloat16(b1.x); o.h[5] = __float2bfloat16(b1.y);
                o.h[6] = __float2bfloat16(b1.z); o.h[7] = __float2bfloat16(b1.w);
                *(bf16x8*)&Bs[dst] = o.v;
            }
            __syncthreads();
#pragma unroll
            for (int ks = 0; ks < 2; ++ks) {
                const int slot = ((ks * 4 + qd) ^ (r & 7)) * 8;
                bf16x8 af[2], bv[2];
#pragma unroll
                for (int mi = 0; mi < 2; ++mi)
                    af[mi] = *(const bf16x8*)&As[(wm + mi * 16 + r) * 64 + slot];
#pragma unroll
                for (int ni = 0; ni < 2; ++ni)
                    bv[ni] = *(const bf16x8*)&Bs[(wn + ni * 16 + r) * 64 + slot];
#pragma unroll
                for (int mi = 0; mi < 2; ++mi)
#pragma unroll
                    for (int ni = 0; ni < 2; ++ni)
                        acc[mi][ni] = MFMA(af[mi], bv[ni], acc[mi][ni]);
            }
            __syncthreads();
        }
        float* Mpb = Mp + (long)kc * 1024 * 1024;
#pragma unroll
        for (int mi = 0; mi < 2; ++mi)
#pragma unroll
            for (int ni = 0; ni < 2; ++ni)
#pragma unroll
                for (int j = 0; j < 4; ++j) {
                    int row = m0 + wm + mi * 16 + qd * 4 + j;   // b
                    int col = n0 + wn + ni * 16 + r;            // a
                    Mpb[(long)row * 1024 + col] = acc[mi][ni][j];
                }
        return;
    }
    if (bid < 9216) {                              // ---- x cast (8192 blocks)
        long i = ((long)(bid - 1024) * 256 + tid) * 4;
        float4 v = *(const float4*)(x + i);
        pack4 o;
        o.h[0] = __float2bfloat16(v.x);
        o.h[1] = __float2bfloat16(v.y);
        o.h[2] = __float2bfloat16(v.z);
        o.h[3] = __float2bfloat16(v.w);
        *(uint2*)(xb + i) = o.u2;
        return;
    }
    if (bid >= 9472) {                             // ---- RS zero (8 blocks)
        int i = (bid - 9472) * 1024 + tid * 4;
        *(float4*)(RS + i) = make_float4(0.f, 0.f, 0.f, 0.f);
        return;
    }
    // ---- Wv transpose (256 blocks)
    const int idx = bid - 9216;                    // 0..255
    const int k0 = (idx >> 4) * 64, n0 = (idx & 15) * 64;
    bf16* t = smem;                                // [64][68]
#pragma unroll
    for (int p = 0; p < 4; ++p) {
        int kr = p * 16 + (tid >> 4);
        int c4 = (tid & 15) * 4;
        float4 v = *(const float4*)&Wv[(long)(k0 + kr) * DOUT + n0 + c4];
        t[(c4 + 0) * 68 + kr] = __float2bfloat16(v.x);
        t[(c4 + 1) * 68 + kr] = __float2bfloat16(v.y);
        t[(c4 + 2) * 68 + kr] = __float2bfloat16(v.z);
        t[(c4 + 3) * 68 + kr] = __float2bfloat16(v.w);
    }
    __syncthreads();
#pragma unroll
    for (int i = 0; i < 2; ++i) {
        int l = tid + i * 256;
        int n = l >> 3, c8 = (l & 7) * 8;
        pack8 o;
#pragma unroll
        for (int j = 0; j < 8; ++j) o.h[j] = t[n * 68 + c8 + j];
        *(bf16x8*)&Wtv[(long)(n0 + n) * DIN + k0 + c8] = o.v;
    }
}

// ---------------- mcast: Mt = bf16(Mp[0]+Mp[1]+Mp[2]+Mp[3]) ----------------

__global__ __launch_bounds__(256)
void k_mcast(const float* __restrict__ Mp, bf16* __restrict__ Mt)
{
    long i = ((long)blockIdx.x * 256 + threadIdx.x) * 16;
#pragma unroll
    for (int e = 0; e < 4; ++e) {
        long o = i + e * 4;
        float4 p0 = *(const float4*)(Mp + o);
        float4 p1 = *(const float4*)(Mp + 1048576 + o);
        float4 p2 = *(const float4*)(Mp + 2097152 + o);
        float4 p3 = *(const float4*)(Mp + 3145728 + o);
        pack4 w;
        w.h[0] = __float2bfloat16(p0.x + p1.x + p2.x + p3.x);
        w.h[1] = __float2bfloat16(p0.y + p1.y + p2.y + p3.y);
        w.h[2] = __float2bfloat16(p0.z + p1.z + p2.z + p3.z);
        w.h[3] = __float2bfloat16(p0.w + p1.w + p2.w + p3.w);
        *(uint2*)(Mt + o) = w.u2;
    }
}

// ---------------- shared GEMM core, BK=64 (round-0 verified) ----------------

template<int DIAG>
__device__ __forceinline__ void gemm_core(
    const bf16* __restrict__ Ab, long lda,
    const bf16* __restrict__ Bb, long ldb,
    int nk, bf16* __restrict__ As, bf16* __restrict__ Bs,
    f32x4 acc[4][4])
{
    const int tid  = threadIdx.x;
    const int lane = tid & 63;
    const int wave = tid >> 6;
    const int wm = (wave >> 1) * 64;
    const int wn = (wave & 1) * 64;
    const int r  = lane & 15;
    const int qd = lane >> 4;

    const bool skipWave = DIAG && (wn > wm);
    const bool sameOff  = DIAG && (wn == wm);

    const int row0 = tid >> 3;                    // 0..31
    const int c    = (tid & 7) ^ (row0 & 7);      // swizzled source chunk
    const long aoff = (long)row0 * lda + c * 8;
    const long boff = (long)row0 * ldb + c * 8;
    const long astep = 32 * lda, bstep = 32 * ldb;
    bf16* dA = &As[tid * 8];
    bf16* dB = &Bs[tid * 8];

    for (int kk = 0; kk < nk; ++kk) {
        const bf16* A = Ab + kk * 64 + aoff;
        const bf16* B = Bb + kk * 64 + boff;
#pragma unroll
        for (int i = 0; i < 4; ++i) {
            gl16(A + i * astep, dA + i * 2048);
            gl16(B + i * bstep, dB + i * 2048);
        }
        __syncthreads();                           // drains vmcnt
        if (!skipWave) {
#pragma unroll
            for (int ks = 0; ks < 2; ++ks) {
                const int slot = ((ks * 4 + qd) ^ (r & 7)) * 8;
                bf16x8 af[4], bv[4];
#pragma unroll
                for (int mi = 0; mi < 4; ++mi)
                    af[mi] = *(const bf16x8*)&As[(wm + mi * 16 + r) * 64 + slot];
#pragma unroll
                for (int ni = 0; ni < 4; ++ni)
                    bv[ni] = *(const bf16x8*)&Bs[(wn + ni * 16 + r) * 64 + slot];
#pragma unroll
                for (int mi = 0; mi < 4; ++mi)
#pragma unroll
                    for (int ni = 0; ni < 4; ++ni) {
                        if (sameOff && ni > mi) continue;   // fully masked
                        acc[mi][ni] = MFMA(af[mi], bv[ni], acc[mi][ni]);
                    }
            }
        }
        __syncthreads();
    }
}

// ---------------- Q'|V projection (16 n-tiles; K eliminated) ----------------

__global__ __launch_bounds__(256)
void k_gemm_qkv(const bf16* __restrict__ xb, const bf16* __restrict__ Mt,
                const bf16* __restrict__ Wtv, bf16* __restrict__ Qp,
                bf16* __restrict__ Vt)
{
    __shared__ __align__(16) bf16 smem[17408];    // As|Bs then T
    bf16* As = smem;
    bf16* Bs = smem + 8192;
    const int m0 = blockIdx.y * 128;
    const int bx = blockIdx.x;
    const int n0 = bx * 128;
    const bf16* Bpan = (bx < 8) ? (Mt + (long)n0 * DIN)
                                : (Wtv + (long)(n0 - 1024) * DIN);
    f32x4 acc[4][4] = {};
    gemm_core<0>(xb + (long)m0 * DIN, DIN, Bpan, DIN, DIN / 64, As, Bs, acc);

    const int tid = threadIdx.x;
    const int lane = tid & 63, wave = tid >> 6;
    const int wm = (wave >> 1) * 64, wn = (wave & 1) * 64;
    const int r = lane & 15, qd = lane >> 4;

    if (bx < 8) {                                  // Q': direct store
#pragma unroll
        for (int mi = 0; mi < 4; ++mi)
#pragma unroll
            for (int ni = 0; ni < 4; ++ni)
#pragma unroll
                for (int j = 0; j < 4; ++j) {
                    int row = m0 + wm + mi * 16 + qd * 4 + j;
                    int col = n0 + wn + ni * 16 + r;
                    Qp[(long)row * 1024 + col] = __float2bfloat16(acc[mi][ni][j]);
                }
    } else {                                       // V: transpose via LDS
        const int ld = 136;
        bf16* T = smem;                            // reuse (post-barrier)
#pragma unroll
        for (int mi = 0; mi < 4; ++mi)
#pragma unroll
            for (int ni = 0; ni < 4; ++ni) {
                pack4 p;
#pragma unroll
                for (int j = 0; j < 4; ++j) p.h[j] = __float2bfloat16(acc[mi][ni][j]);
                int d_l = wn + ni * 16 + r;
                int s_l = wm + mi * 16 + qd * 4;
                *(uint2*)&T[d_l * ld + s_l] = p.u2;
            }
        __syncthreads();
        const int n0v = n0 - 1024;
        const int bb = m0 >> 11;                   // batch index
        const int s0 = m0 & 2047;                  // seq offset within batch
        bf16* Ob = Vt + (long)bb * DOUT * SEQ + s0;
#pragma unroll
        for (int p = 0; p < 8; ++p) {
            int l = tid + p * 256;                 // 0..2047
            int d = l >> 4, s8 = (l & 15) * 8;
            bf16x8 vv = *(const bf16x8*)&T[d * ld + s8];
            *(bf16x8*)&Ob[(long)(n0v + d) * SEQ + s8] = vv;
        }
    }
}

// ---------------- scores: (Q' @ xb^T), exp, row-sum (round-9 layout) --------

__global__ __launch_bounds__(256, 3)
void k_gemm_scores(const bf16* __restrict__ Qp, const bf16* __restrict__ xb,
                   bf16* __restrict__ P, float* __restrict__ rowSum)
{
    const int bid = blockIdx.x;
    int b, qt, kt, u = -1, d = -1;
    if      (bid < 256) u = bid;
    else if (bid < 288) d = bid - 256;
    else if (bid < 512) u = bid - 32;
    else                d = bid - 480;
    if (u >= 0) {
        b = u & 3;
        int v = u >> 2;                            // 0..119, heavy qt first
        qt = 15;
        while (v >= qt) { v -= qt; --qt; }
        kt = v;                                    // kt < qt
    } else { b = d & 3; qt = kt = d >> 2; }

    __shared__ __align__(16) bf16 smem[17408];     // As|Bs then bounce tile
    bf16* As = smem;
    bf16* Bs = smem + 8192;
    const bf16* A  = Qp + (long)(b * SEQ + qt * 128) * 1024;
    const bf16* Bt = xb + (long)(b * SEQ + kt * 128) * 1024;
    f32x4 acc[4][4] = {};
    if (u >= 0) gemm_core<0>(A, 1024, Bt, 1024, DIN / 64, As, Bs, acc);
    else        gemm_core<1>(A, 1024, Bt, 1024, DIN / 64, As, Bs, acc);

    bf16* Pb = P + (long)b * SEQ * SEQ;
    float* RS = rowSum + b * SEQ;
    const int tid = threadIdx.x;
    const int lane = tid & 63, wave = tid >> 6;
    const int wm = (wave >> 1) * 64, wn = (wave & 1) * 64;
    const int r = lane & 15, qd = lane >> 4;

    const int ld = 136;                            // bounce-tile stride
    bf16* T = smem;                                // reuse (post-barrier)

    float rp[4][4];
#pragma unroll
    for (int mi = 0; mi < 4; ++mi)
#pragma unroll
        for (int j = 0; j < 4; ++j) rp[mi][j] = 0.f;

#pragma unroll
    for (int mi = 0; mi < 4; ++mi)
#pragma unroll
        for (int ni = 0; ni < 4; ++ni)
#pragma unroll
            for (int j = 0; j < 4; ++j) {
                int row_l = wm + mi * 16 + qd * 4 + j;
                int col_l = wn + ni * 16 + r;
                int row = qt * 128 + row_l;
                int col = kt * 128 + col_l;
                float e = (col > row) ? 0.f : __expf(acc[mi][ni][j] * 0.03125f);
                rp[mi][j] += e;
                T[row_l * ld + col_l] = __float2bfloat16(e);
            }
#pragma unroll
    for (int dd = 1; dd < 16; dd <<= 1)
#pragma unroll
        for (int mi = 0; mi < 4; ++mi)
#pragma unroll
            for (int j = 0; j < 4; ++j)
                rp[mi][j] += __shfl_xor(rp[mi][j], dd, 64);
    if (r == 0) {
#pragma unroll
        for (int mi = 0; mi < 4; ++mi)
#pragma unroll
            for (int j = 0; j < 4; ++j) {
                int row = qt * 128 + wm + mi * 16 + qd * 4 + j;
                atomicAdd(&RS[row], rp[mi][j]);
            }
    }
    __syncthreads();
    // bulk coalesced P store: 128x128 tile, b128 per thread x8
#pragma unroll
    for (int p = 0; p < 8; ++p) {
        int l = tid + p * 256;                     // 0..2047
        int row_l = l >> 4, c8 = (l & 15) * 8;
        bf16x8 vv = *(const bf16x8*)&T[row_l * ld + c8];
        *(bf16x8*)&Pb[(long)(qt * 128 + row_l) * SEQ + kt * 128 + c8] = vv;
    }
}

// ---------------- PV: O = (P @ V) / rowSum (round-6 verified) ----------------

__global__ __launch_bounds__(256, 3)
void k_gemm_pv(const bf16* __restrict__ P, const bf16* __restrict__ Vt,
               const float* __restrict__ rowSum, float* __restrict__ O)
{
    const int bid = blockIdx.x;                    // 0..511
    const int h   = bid & 255;
    const int qt  = (bid < 256) ? (15 - (h >> 5)) : (h >> 5);
    const int b   = (h >> 3) & 3;
    const int nt  = h & 7;
    __shared__ __align__(16) bf16 As[128 * 64];
    __shared__ __align__(16) bf16 Bs[128 * 64];
    const bf16* A  = P + (long)b * SEQ * SEQ + (long)qt * 128 * SEQ;
    const bf16* Bt = Vt + (long)b * DOUT * SEQ;
    const int nk = (qt + 1) * 2;                   // K up to (qt+1)*128, BK=64
    f32x4 acc[4][4] = {};
    gemm_core<0>(A, SEQ, Bt + (long)nt * 128 * SEQ, SEQ, nk, As, Bs, acc);

    float* Ob = O + (long)b * SEQ * DOUT;
    const float* RS = rowSum + b * SEQ;
    const int lane = threadIdx.x & 63, wave = threadIdx.x >> 6;
    const int wm = (wave >> 1) * 64, wn = (wave & 1) * 64;
    const int r = lane & 15, qd = lane >> 4;
#pragma unroll
    for (int mi = 0; mi < 4; ++mi)
#pragma unroll
        for (int j = 0; j < 4; ++j) {
            int row = qt * 128 + wm + mi * 16 + qd * 4 + j;
            float inv = 1.0f / RS[row];
#pragma unroll
            for (int ni = 0; ni < 4; ++ni) {
                int col = nt * 128 + wn + ni * 16 + r;
                Ob[(long)row * DOUT + col] = acc[mi][ni][j] * inv;
            }
        }
}

// ---------------- launch ----------------

extern "C" void kernel_launch(void* const* d_in, const int* in_sizes, int n_in,
                              void* d_out, int out_size, void* d_ws, size_t ws_size,
                              hipStream_t stream)
{
    const float* x  = (const float*)d_in[0];
    const float* Wq = (const float*)d_in[1];
    const float* Wk = (const float*)d_in[2];
    const float* Wv = (const float*)d_in[3];
    float* out = (float*)d_out;

    char* ws = (char*)d_ws;
    bf16*  xb  = (bf16*)(ws);                       // 16 MiB
    bf16*  Wtv = (bf16*)(ws + 16777216);            //  2 MiB
    bf16*  Mt  = (bf16*)(ws + 18874368);            //  2 MiB
    bf16*  Qp  = (bf16*)(ws + 20971520);            // 16 MiB
    bf16*  Vt  = (bf16*)(ws + 37748736);            // 16 MiB
    bf16*  P   = (bf16*)(ws + 54525952);            // 32 MiB
    float* RS  = (float*)(ws + 88080384);           // 32 KiB
    float* Mp  = (float*)(ws + 88113152);           // 16 MiB fp32 partials

    k_prep<<<dim3(1024 + 8192 + 256 + 8), 256, 0, stream>>>(
        x, Wq, Wk, Wv, xb, Wtv, Mp, RS);
    k_mcast<<<dim3(256), 256, 0, stream>>>(Mp, Mt);
    k_gemm_qkv<<<dim3(16, MTOT / 128), 256, 0, stream>>>(xb, Mt, Wtv, Qp, Vt);
    k_gemm_scores<<<dim3(544), 256, 0, stream>>>(Qp, xb, P, RS);
    k_gemm_pv<<<dim3(512), 256, 0, stream>>>(P, Vt, RS, out);
}